// Round 1
// baseline (475.023 us; speedup 1.0000x reference)
//
#include <hip/hip_runtime.h>

#define D_DIRS 4
#define BB 2
#define CC 96
#define LL 4096
#define PP 192
#define TWOP 384
#define NN 16
#define DTR 6
#define NPROJ 38
#define NCH 64
#define CLEN 64

// time index t (within a direction's sequence) -> flat pixel offset h*64+w in x1
__device__ __forceinline__ int pixoff(int d, int t) {
    int tt = (d & 1) ? (LL - 1 - t) : t;
    if (d < 2) return tt;                      // seq_h: l = h*W + w
    return ((tt & 63) << 6) | (tt >> 6);       // seq_w: l = w*H + h -> pixel h*W+w
}

// ---------------- input GEMM: xz[m][j] = sum_c seq[m][c] * W_in[d][j][c] ----------------
__global__ __launch_bounds__(256) void k_gemm_in(
    const float* __restrict__ x1, const float* __restrict__ W_in, float* __restrict__ xz)
{
    __shared__ __align__(16) float As[CC * 32];   // [c][t]
    __shared__ __align__(16) float Bs[64 * 97];   // [j][c] padded stride 97
    const int db = blockIdx.z;
    const int d = db >> 1, b = db & 1;
    const int t0 = blockIdx.x * 32;
    const int j0 = blockIdx.y * 64;
    const int tid = threadIdx.x;

    for (int i = tid; i < CC * 32; i += 256) {
        int t = i & 31, c = i >> 5;
        int pix = pixoff(d, t0 + t);
        As[c * 32 + t] = x1[(b * CC + c) * LL + pix];
    }
    const float* Wd = W_in + d * TWOP * CC;
    for (int i = tid; i < 64 * CC; i += 256) {
        int c = i % CC, j = i / CC;
        Bs[j * 97 + c] = Wd[(j0 + j) * CC + c];
    }
    __syncthreads();

    const int jl = tid & 63;
    const int tg = (tid >> 6) * 8;
    float acc[8] = {0, 0, 0, 0, 0, 0, 0, 0};
    for (int k = 0; k < CC; ++k) {
        float bv = Bs[jl * 97 + k];
        const float4 a0 = *reinterpret_cast<const float4*>(&As[k * 32 + tg]);
        const float4 a1 = *reinterpret_cast<const float4*>(&As[k * 32 + tg + 4]);
        acc[0] += a0.x * bv; acc[1] += a0.y * bv; acc[2] += a0.z * bv; acc[3] += a0.w * bv;
        acc[4] += a1.x * bv; acc[5] += a1.y * bv; acc[6] += a1.z * bv; acc[7] += a1.w * bv;
    }
    long base = ((long)(db * LL + t0 + tg)) * TWOP + j0 + jl;
#pragma unroll
    for (int i = 0; i < 8; ++i) xz[base + (long)i * TWOP] = acc[i];
}

// ---------------- depthwise causal conv (k=4) + bias + SiLU ----------------
__global__ void k_conv(const float* __restrict__ xz, const float* __restrict__ conv_w,
                       const float* __restrict__ conv_b, float* __restrict__ xbuf)
{
    int idx = blockIdx.x * blockDim.x + threadIdx.x;
    const int total = D_DIRS * BB * LL * PP;
    for (; idx < total; idx += gridDim.x * blockDim.x) {
        int p = idx % PP;
        int m = idx / PP;
        int t = m & (LL - 1);
        int d = m >> 13;
        float acc = conv_b[d * PP + p];
        const float* wp = conv_w + (d * PP + p) * 4;
#pragma unroll
        for (int k = 0; k < 4; ++k) {
            int tt = t - 3 + k;
            if (tt >= 0) acc += wp[k] * xz[(long)(m - 3 + k) * TWOP + p];
        }
        xbuf[(long)m * PP + p] = acc / (1.0f + __expf(-acc));
    }
}

// ---------------- plain GEMM: out[m][j] = sum_k A[m][k] * Wt[d][j][k], K=192 ----------------
template <int J>
__global__ __launch_bounds__(256) void k_gemm_plain(
    const float* __restrict__ A, const float* __restrict__ Wt, float* __restrict__ out)
{
    __shared__ __align__(16) float As[PP * 33];   // [k][t] stride 33
    __shared__ __align__(16) float Bs[32 * 193];  // [j][k] stride 193
    const int m0 = blockIdx.x * 32;
    const int d = m0 >> 13;
    const int j0 = blockIdx.y * 32;
    const int tid = threadIdx.x;

    for (int i = tid; i < PP * 32; i += 256) {
        int k = i % PP, t = i / PP;
        As[k * 33 + t] = A[(long)(m0 + t) * PP + k];
    }
    const float* Wd = Wt + d * J * PP;
    for (int i = tid; i < 32 * PP; i += 256) {
        int k = i % PP, j = i / PP;
        int jg = j0 + j;
        Bs[j * 193 + k] = (jg < J) ? Wd[jg * PP + k] : 0.0f;
    }
    __syncthreads();

    const int jl = tid & 31;
    const int tg = tid >> 5;  // 0..7
    float acc[4] = {0, 0, 0, 0};
    for (int k = 0; k < PP; ++k) {
        float bv = Bs[jl * 193 + k];
#pragma unroll
        for (int i = 0; i < 4; ++i)
            acc[i] += As[k * 33 + tg + 8 * i] * bv;
    }
    if (j0 + jl < J) {
#pragma unroll
        for (int i = 0; i < 4; ++i) {
            int m = m0 + tg + 8 * i;
            out[(long)m * J + j0 + jl] = acc[i];
        }
    }
}

// ---------------- dt = softplus(proj[:, :6] @ W_dt^T + b_dt) ----------------
__global__ void k_dt(const float* __restrict__ proj, const float* __restrict__ W_dt,
                     const float* __restrict__ b_dt, float* __restrict__ dt)
{
    int idx = blockIdx.x * blockDim.x + threadIdx.x;
    const int total = D_DIRS * BB * LL * PP;
    for (; idx < total; idx += gridDim.x * blockDim.x) {
        int p = idx % PP;
        int m = idx / PP;
        int d = m >> 13;
        float v = b_dt[d * PP + p];
        const float* wp = W_dt + (d * PP + p) * DTR;
        const float* pr = proj + (long)m * NPROJ;
#pragma unroll
        for (int r = 0; r < DTR; ++r) v += wp[r] * pr[r];
        dt[idx] = (v > 20.0f) ? v : log1pf(__expf(v));
    }
}

// ---------------- scan pass 1: per-chunk (prod dA, local h) ----------------
__global__ __launch_bounds__(256) void k_pass1(
    const float* __restrict__ dt, const float* __restrict__ xbuf,
    const float* __restrict__ proj, const float* __restrict__ A_log,
    float* __restrict__ cb)
{
    const int tid = threadIdx.x;
    const int n = tid & 15;
    const int pl = tid >> 4;
    const int p = blockIdx.x * 16 + pl;
    const int chunk = blockIdx.y;
    const int db = blockIdx.z;
    const int d = db >> 1;
    const float Av = -__expf(A_log[(d * PP + p) * NN + n]);
    const long mb = (long)db * LL + chunk * CLEN;
    float h = 0.0f, pa = 1.0f;
#pragma unroll 4
    for (int s = 0; s < CLEN; ++s) {
        long m = mb + s;
        float dtv = dt[m * PP + p];
        float xv = xbuf[m * PP + p];
        float bv = proj[m * NPROJ + DTR + n];
        float dA = __expf(dtv * Av);
        h = dA * h + dtv * xv * bv;
        pa *= dA;
    }
    long ci = ((long)(db * PP + p) * NN + n) * (NCH * 2) + chunk * 2;
    cb[ci] = pa;
    cb[ci + 1] = h;
}

// ---------------- serial scan over chunks -> initial states ----------------
__global__ void k_chunkscan(float* __restrict__ cb)
{
    int idx = blockIdx.x * blockDim.x + threadIdx.x;  // 0..24575 = (db*P+p)*16+n
    float* base = cb + (long)idx * (NCH * 2);
    float run = 0.0f;
    for (int c = 0; c < NCH; ++c) {
        float pa = base[2 * c];
        float hc = base[2 * c + 1];
        base[2 * c + 1] = run;           // h_init for chunk c
        run = pa * run + hc;
    }
}

// ---------------- scan pass 2: emit y = (sum_n h*C + x*Dp) * silu(z) ----------------
__global__ __launch_bounds__(256) void k_pass2(
    const float* __restrict__ dt, const float* xbuf_in,
    const float* __restrict__ proj, const float* __restrict__ A_log,
    const float* __restrict__ Dp, const float* __restrict__ xz,
    const float* __restrict__ cb, float* ys)  // ys aliases xbuf_in (safe: read-before-write per element)
{
    const int tid = threadIdx.x;
    const int n = tid & 15;
    const int pl = tid >> 4;
    const int p = blockIdx.x * 16 + pl;
    const int chunk = blockIdx.y;
    const int db = blockIdx.z;
    const int d = db >> 1;
    const float Av = -__expf(A_log[(d * PP + p) * NN + n]);
    const float Dv = Dp[d * PP + p];
    const long mb = (long)db * LL + chunk * CLEN;
    long ci = ((long)(db * PP + p) * NN + n) * (NCH * 2) + chunk * 2;
    float h = cb[ci + 1];
#pragma unroll 2
    for (int s = 0; s < CLEN; ++s) {
        long m = mb + s;
        float dtv = dt[m * PP + p];
        float xv = xbuf_in[m * PP + p];
        float bv = proj[m * NPROJ + DTR + n];
        float cv = proj[m * NPROJ + DTR + NN + n];
        float dA = __expf(dtv * Av);
        h = dA * h + dtv * xv * bv;
        float part = h * cv;
        part += __shfl_xor(part, 1, 16);
        part += __shfl_xor(part, 2, 16);
        part += __shfl_xor(part, 4, 16);
        part += __shfl_xor(part, 8, 16);
        if (n == 0) {
            float zv = xz[m * TWOP + PP + p];
            ys[m * PP + p] = (part + xv * Dv) * (zv / (1.0f + __expf(-zv)));
        }
    }
}

// ---------------- final combine: out = x2 + sum of 4 directional outputs ----------------
__global__ void k_final(const float* __restrict__ x2, const float* __restrict__ yo,
                        float* __restrict__ out)
{
    int idx = blockIdx.x * blockDim.x + threadIdx.x;
    const int total = BB * CC * LL;
    for (; idx < total; idx += gridDim.x * blockDim.x) {
        int w = idx & 63;
        int h = (idx >> 6) & 63;
        int c = (idx >> 12) % CC;
        int b = idx / (CC * LL);
        int lh = (h << 6) | w;
        int lw = (w << 6) | h;
        long m0 = (long)(0 * BB + b) * LL + lh;
        long m1 = (long)(1 * BB + b) * LL + (LL - 1 - lh);
        long m2 = (long)(2 * BB + b) * LL + lw;
        long m3 = (long)(3 * BB + b) * LL + (LL - 1 - lw);
        out[idx] = x2[idx] + yo[m0 * CC + c] + yo[m1 * CC + c] + yo[m2 * CC + c] + yo[m3 * CC + c];
    }
}

extern "C" void kernel_launch(void* const* d_in, const int* in_sizes, int n_in,
                              void* d_out, int out_size, void* d_ws, size_t ws_size,
                              hipStream_t stream)
{
    const float* x1     = (const float*)d_in[0];
    const float* x2     = (const float*)d_in[1];
    const float* W_in   = (const float*)d_in[2];
    const float* conv_w = (const float*)d_in[3];
    const float* conv_b = (const float*)d_in[4];
    const float* W_x    = (const float*)d_in[5];
    const float* W_dt   = (const float*)d_in[6];
    const float* b_dt   = (const float*)d_in[7];
    const float* A_log  = (const float*)d_in[8];
    const float* Dp     = (const float*)d_in[9];
    const float* W_out  = (const float*)d_in[10];
    float* out = (float*)d_out;
    float* ws  = (float*)d_ws;

    // workspace layout (floats)
    float* xz   = ws;                 // 4*2*4096*384 = 12,582,912
    float* xbuf = ws + 12582912;      // 6,291,456  (later reused in-place as ys)
    float* proj = ws + 18874368;      // 32768*38 = 1,245,184
    float* dtb  = ws + 20119552;      // 6,291,456  (later reused as yo: 3,145,728)
    float* cb   = ws + 26411008;      // 4*2*192*16*64*2 = 3,145,728
    float* ys = xbuf;
    float* yo = dtb;

    k_gemm_in<<<dim3(128, 6, 8), 256, 0, stream>>>(x1, W_in, xz);
    k_conv<<<dim3(6144), 256, 0, stream>>>(xz, conv_w, conv_b, xbuf);
    k_gemm_plain<NPROJ><<<dim3(1024, 2), 256, 0, stream>>>(xbuf, W_x, proj);
    k_dt<<<dim3(6144), 256, 0, stream>>>(proj, W_dt, b_dt, dtb);
    k_pass1<<<dim3(12, 64, 8), 256, 0, stream>>>(dtb, xbuf, proj, A_log, cb);
    k_chunkscan<<<dim3(96), 256, 0, stream>>>(cb);
    k_pass2<<<dim3(12, 64, 8), 256, 0, stream>>>(dtb, xbuf, proj, A_log, Dp, xz, cb, ys);
    k_gemm_plain<CC><<<dim3(1024, 3), 256, 0, stream>>>(ys, W_out, yo);
    k_final<<<dim3(3072), 256, 0, stream>>>(x2, yo, out);
}

// Round 2
// 360.654 us; speedup vs baseline: 1.3171x; 1.3171x over previous
//
#include <hip/hip_runtime.h>

#define D_DIRS 4
#define BB 2
#define CC 96
#define LL 4096
#define PP 192
#define TWOP 384
#define NN 16
#define DTR 6
#define NPROJ 38
#define NCH 128
#define CLEN 32
#define SEQT 24576   // 8 db * 192 p * 16 n

// time index t (within a direction's sequence) -> flat pixel offset h*64+w in x1
__device__ __forceinline__ int pixoff(int d, int t) {
    int tt = (d & 1) ? (LL - 1 - t) : t;
    if (d < 2) return tt;                      // seq_h: l = h*W + w
    return ((tt & 63) << 6) | (tt >> 6);       // seq_w: l = w*H + h -> pixel h*W+w
}

// ---------------- input GEMM: xz[m][j] = sum_c seq[m][c] * W_in[d][j][c] ----------------
__global__ __launch_bounds__(256) void k_gemm_in(
    const float* __restrict__ x1, const float* __restrict__ W_in, float* __restrict__ xz)
{
    __shared__ __align__(16) float As[CC * 32];   // [c][t]
    __shared__ __align__(16) float Bs[64 * 97];   // [j][c] padded stride 97
    const int db = blockIdx.z;
    const int d = db >> 1, b = db & 1;
    const int t0 = blockIdx.x * 32;
    const int j0 = blockIdx.y * 64;
    const int tid = threadIdx.x;

    for (int i = tid; i < CC * 32; i += 256) {
        int t = i & 31, c = i >> 5;
        int pix = pixoff(d, t0 + t);
        As[c * 32 + t] = x1[(b * CC + c) * LL + pix];
    }
    const float* Wd = W_in + d * TWOP * CC;
    for (int i = tid; i < 64 * CC; i += 256) {
        int c = i % CC, j = i / CC;
        Bs[j * 97 + c] = Wd[(j0 + j) * CC + c];
    }
    __syncthreads();

    const int jl = tid & 63;
    const int tg = (tid >> 6) * 8;
    float acc[8] = {0, 0, 0, 0, 0, 0, 0, 0};
    for (int k = 0; k < CC; ++k) {
        float bv = Bs[jl * 97 + k];
        const float4 a0 = *reinterpret_cast<const float4*>(&As[k * 32 + tg]);
        const float4 a1 = *reinterpret_cast<const float4*>(&As[k * 32 + tg + 4]);
        acc[0] += a0.x * bv; acc[1] += a0.y * bv; acc[2] += a0.z * bv; acc[3] += a0.w * bv;
        acc[4] += a1.x * bv; acc[5] += a1.y * bv; acc[6] += a1.z * bv; acc[7] += a1.w * bv;
    }
    long base = ((long)(db * LL + t0 + tg)) * TWOP + j0 + jl;
#pragma unroll
    for (int i = 0; i < 8; ++i) xz[base + (long)i * TWOP] = acc[i];
}

// ---------------- depthwise causal conv (k=4) + bias + SiLU ----------------
__global__ void k_conv(const float* __restrict__ xz, const float* __restrict__ conv_w,
                       const float* __restrict__ conv_b, float* __restrict__ xbuf)
{
    int idx = blockIdx.x * blockDim.x + threadIdx.x;
    const int total = D_DIRS * BB * LL * PP;
    for (; idx < total; idx += gridDim.x * blockDim.x) {
        int p = idx % PP;
        int m = idx / PP;
        int t = m & (LL - 1);
        int d = m >> 13;
        float acc = conv_b[d * PP + p];
        const float* wp = conv_w + (d * PP + p) * 4;
#pragma unroll
        for (int k = 0; k < 4; ++k) {
            int tt = t - 3 + k;
            if (tt >= 0) acc += wp[k] * xz[(long)(m - 3 + k) * TWOP + p];
        }
        xbuf[(long)m * PP + p] = acc / (1.0f + __expf(-acc));
    }
}

// ---------------- plain GEMM: out[m][j] = sum_k A[m][k] * Wt[d][j][k], K=192 ----------------
template <int J>
__global__ __launch_bounds__(256) void k_gemm_plain(
    const float* __restrict__ A, const float* __restrict__ Wt, float* __restrict__ out)
{
    __shared__ __align__(16) float As[PP * 33];   // [k][t] stride 33
    __shared__ __align__(16) float Bs[32 * 193];  // [j][k] stride 193
    const int m0 = blockIdx.x * 32;
    const int d = m0 >> 13;
    const int j0 = blockIdx.y * 32;
    const int tid = threadIdx.x;

    for (int i = tid; i < PP * 32; i += 256) {
        int k = i % PP, t = i / PP;
        As[k * 33 + t] = A[(long)(m0 + t) * PP + k];
    }
    const float* Wd = Wt + d * J * PP;
    for (int i = tid; i < 32 * PP; i += 256) {
        int k = i % PP, j = i / PP;
        int jg = j0 + j;
        Bs[j * 193 + k] = (jg < J) ? Wd[jg * PP + k] : 0.0f;
    }
    __syncthreads();

    const int jl = tid & 31;
    const int tg = tid >> 5;  // 0..7
    float acc[4] = {0, 0, 0, 0};
    for (int k = 0; k < PP; ++k) {
        float bv = Bs[jl * 193 + k];
#pragma unroll
        for (int i = 0; i < 4; ++i)
            acc[i] += As[k * 33 + tg + 8 * i] * bv;
    }
    if (j0 + jl < J) {
#pragma unroll
        for (int i = 0; i < 4; ++i) {
            int m = m0 + tg + 8 * i;
            out[(long)m * J + j0 + jl] = acc[i];
        }
    }
}

// ---------------- scan pass 1: 1 thread per (p,chunk,db), 16 states in regs ----------------
__global__ __launch_bounds__(192) void k_pass1(
    const float* __restrict__ xbuf, const float* __restrict__ proj,
    const float* __restrict__ A_log, const float* __restrict__ W_dt,
    const float* __restrict__ b_dt,
    float* __restrict__ cb_pa, float* __restrict__ cb_h)
{
    __shared__ __align__(16) float pl[CLEN * 40];  // cols 0..5 = dtproj, 8..23 = B, 24..39 = C
    const int tid = threadIdx.x;      // = p
    const int chunk = blockIdx.x;
    const int db = blockIdx.y;
    const int d = db >> 1;
    const int m0 = db * LL + chunk * CLEN;

    const float* pr = proj + (long)m0 * NPROJ;
    for (int i = tid; i < CLEN * NPROJ; i += 192) {
        int r = i / NPROJ, c = i - r * NPROJ;
        int col = (c < 6) ? c : c + 2;
        pl[r * 40 + col] = pr[i];
    }

    const int p = tid;
    float A[16];
    const float* al = A_log + (d * PP + p) * NN;
#pragma unroll
    for (int n = 0; n < 16; ++n) A[n] = -__expf(al[n]);
    float w[6];
    const float* wd = W_dt + (d * PP + p) * DTR;
#pragma unroll
    for (int r = 0; r < 6; ++r) w[r] = wd[r];
    const float bdt = b_dt[d * PP + p];
    float h[16], pa[16];
#pragma unroll
    for (int n = 0; n < 16; ++n) { h[n] = 0.f; pa[n] = 1.f; }
    __syncthreads();

    const float* xp = xbuf + m0 * PP + p;
#pragma unroll 2
    for (int s = 0; s < CLEN; ++s) {
        const float* row = pl + s * 40;
        float v = bdt + row[0]*w[0] + row[1]*w[1] + row[2]*w[2]
                      + row[3]*w[3] + row[4]*w[4] + row[5]*w[5];
        float dtv = (v > 20.f) ? v : log1pf(__expf(v));
        float xv = xp[s * PP];
        float dtx = dtv * xv;
        const float4* B4 = reinterpret_cast<const float4*>(row + 8);
#pragma unroll
        for (int q = 0; q < 4; ++q) {
            float4 Bv = B4[q];
            float dA;
            dA = __expf(dtv * A[4*q+0]); h[4*q+0] = dA*h[4*q+0] + dtx*Bv.x; pa[4*q+0] *= dA;
            dA = __expf(dtv * A[4*q+1]); h[4*q+1] = dA*h[4*q+1] + dtx*Bv.y; pa[4*q+1] *= dA;
            dA = __expf(dtv * A[4*q+2]); h[4*q+2] = dA*h[4*q+2] + dtx*Bv.z; pa[4*q+2] *= dA;
            dA = __expf(dtv * A[4*q+3]); h[4*q+3] = dA*h[4*q+3] + dtx*Bv.w; pa[4*q+3] *= dA;
        }
    }
    const int seq = db * (PP * NN) + p * NN;
    float4* pao = reinterpret_cast<float4*>(cb_pa + (long)chunk * SEQT + seq);
    float4* ho  = reinterpret_cast<float4*>(cb_h  + (long)chunk * SEQT + seq);
#pragma unroll
    for (int q = 0; q < 4; ++q) {
        pao[q] = make_float4(pa[4*q], pa[4*q+1], pa[4*q+2], pa[4*q+3]);
        ho[q]  = make_float4(h[4*q],  h[4*q+1],  h[4*q+2],  h[4*q+3]);
    }
}

// ---------------- serial scan over chunks -> initial states ----------------
__global__ void k_chunkscan(const float* __restrict__ cb_pa, float* __restrict__ cb_h)
{
    int seq = blockIdx.x * 256 + threadIdx.x;   // 0..24575
    float run = 0.0f;
    for (int c = 0; c < NCH; ++c) {
        long o = (long)c * SEQT + seq;
        float pav = cb_pa[o];
        float hv = cb_h[o];
        cb_h[o] = run;
        run = pav * run + hv;
    }
}

// ---------------- scan pass 2: emit ys = (sum_n h*C + x*Dp) * silu(z) ----------------
__global__ __launch_bounds__(192) void k_pass2(
    const float* xbuf_in, const float* __restrict__ proj,
    const float* __restrict__ A_log, const float* __restrict__ W_dt,
    const float* __restrict__ b_dt, const float* __restrict__ Dp,
    const float* __restrict__ xz, const float* __restrict__ cb_h,
    float* ys)   // ys aliases xbuf_in: each element read-then-written by same thread
{
    __shared__ __align__(16) float pl[CLEN * 40];
    const int tid = threadIdx.x;
    const int chunk = blockIdx.x;
    const int db = blockIdx.y;
    const int d = db >> 1;
    const int m0 = db * LL + chunk * CLEN;

    const float* pr = proj + (long)m0 * NPROJ;
    for (int i = tid; i < CLEN * NPROJ; i += 192) {
        int r = i / NPROJ, c = i - r * NPROJ;
        int col = (c < 6) ? c : c + 2;
        pl[r * 40 + col] = pr[i];
    }

    const int p = tid;
    float A[16];
    const float* al = A_log + (d * PP + p) * NN;
#pragma unroll
    for (int n = 0; n < 16; ++n) A[n] = -__expf(al[n]);
    float w[6];
    const float* wd = W_dt + (d * PP + p) * DTR;
#pragma unroll
    for (int r = 0; r < 6; ++r) w[r] = wd[r];
    const float bdt = b_dt[d * PP + p];
    const float Dv = Dp[d * PP + p];

    float h[16];
    const int seq = db * (PP * NN) + p * NN;
    const float4* hi = reinterpret_cast<const float4*>(cb_h + (long)chunk * SEQT + seq);
#pragma unroll
    for (int q = 0; q < 4; ++q) {
        float4 hv = hi[q];
        h[4*q] = hv.x; h[4*q+1] = hv.y; h[4*q+2] = hv.z; h[4*q+3] = hv.w;
    }
    __syncthreads();

    const float* xp = xbuf_in + m0 * PP + p;
    const float* zp = xz + (long)m0 * TWOP + PP + p;
    float* yp = ys + m0 * PP + p;
#pragma unroll 2
    for (int s = 0; s < CLEN; ++s) {
        const float* row = pl + s * 40;
        float v = bdt + row[0]*w[0] + row[1]*w[1] + row[2]*w[2]
                      + row[3]*w[3] + row[4]*w[4] + row[5]*w[5];
        float dtv = (v > 20.f) ? v : log1pf(__expf(v));
        float xv = xp[s * PP];
        float dtx = dtv * xv;
        const float4* B4 = reinterpret_cast<const float4*>(row + 8);
        const float4* C4 = reinterpret_cast<const float4*>(row + 24);
        float y = 0.0f;
#pragma unroll
        for (int q = 0; q < 4; ++q) {
            float4 Bv = B4[q];
            float4 Cv = C4[q];
            float dA;
            dA = __expf(dtv * A[4*q+0]); h[4*q+0] = dA*h[4*q+0] + dtx*Bv.x; y += h[4*q+0]*Cv.x;
            dA = __expf(dtv * A[4*q+1]); h[4*q+1] = dA*h[4*q+1] + dtx*Bv.y; y += h[4*q+1]*Cv.y;
            dA = __expf(dtv * A[4*q+2]); h[4*q+2] = dA*h[4*q+2] + dtx*Bv.z; y += h[4*q+2]*Cv.z;
            dA = __expf(dtv * A[4*q+3]); h[4*q+3] = dA*h[4*q+3] + dtx*Bv.w; y += h[4*q+3]*Cv.w;
        }
        float zv = zp[s * TWOP];
        yp[s * PP] = (y + xv * Dv) * (zv / (1.0f + __expf(-zv)));
    }
}

// ---------------- final combine: out = x2 + sum of 4 directional outputs ----------------
__global__ void k_final(const float* __restrict__ x2, const float* __restrict__ yo,
                        float* __restrict__ out)
{
    int idx = blockIdx.x * blockDim.x + threadIdx.x;
    const int total = BB * CC * LL;
    for (; idx < total; idx += gridDim.x * blockDim.x) {
        int w = idx & 63;
        int h = (idx >> 6) & 63;
        int c = (idx >> 12) % CC;
        int b = idx / (CC * LL);
        int lh = (h << 6) | w;
        int lw = (w << 6) | h;
        long m0 = (long)(0 * BB + b) * LL + lh;
        long m1 = (long)(1 * BB + b) * LL + (LL - 1 - lh);
        long m2 = (long)(2 * BB + b) * LL + lw;
        long m3 = (long)(3 * BB + b) * LL + (LL - 1 - lw);
        out[idx] = x2[idx] + yo[m0 * CC + c] + yo[m1 * CC + c] + yo[m2 * CC + c] + yo[m3 * CC + c];
    }
}

extern "C" void kernel_launch(void* const* d_in, const int* in_sizes, int n_in,
                              void* d_out, int out_size, void* d_ws, size_t ws_size,
                              hipStream_t stream)
{
    const float* x1     = (const float*)d_in[0];
    const float* x2     = (const float*)d_in[1];
    const float* W_in   = (const float*)d_in[2];
    const float* conv_w = (const float*)d_in[3];
    const float* conv_b = (const float*)d_in[4];
    const float* W_x    = (const float*)d_in[5];
    const float* W_dt   = (const float*)d_in[6];
    const float* b_dt   = (const float*)d_in[7];
    const float* A_log  = (const float*)d_in[8];
    const float* Dp     = (const float*)d_in[9];
    const float* W_out  = (const float*)d_in[10];
    float* out = (float*)d_out;
    float* ws  = (float*)d_ws;

    // workspace layout (floats)
    float* xz    = ws;                // 12,582,912
    float* xbuf  = ws + 12582912;     // 6,291,456  (reused in-place as ys)
    float* proj  = ws + 18874368;     // 1,245,184
    float* cb_pa = ws + 20119552;     // 3,145,728
    float* cb_h  = ws + 23265280;     // 3,145,728
    float* yo    = ws + 26411008;     // 3,145,728
    float* ys = xbuf;

    k_gemm_in<<<dim3(128, 6, 8), 256, 0, stream>>>(x1, W_in, xz);
    k_conv<<<dim3(6144), 256, 0, stream>>>(xz, conv_w, conv_b, xbuf);
    k_gemm_plain<NPROJ><<<dim3(1024, 2), 256, 0, stream>>>(xbuf, W_x, proj);
    k_pass1<<<dim3(NCH, 8), 192, 0, stream>>>(xbuf, proj, A_log, W_dt, b_dt, cb_pa, cb_h);
    k_chunkscan<<<dim3(SEQT / 256), 256, 0, stream>>>(cb_pa, cb_h);
    k_pass2<<<dim3(NCH, 8), 192, 0, stream>>>(xbuf, proj, A_log, W_dt, b_dt, Dp, xz, cb_h, ys);
    k_gemm_plain<CC><<<dim3(1024, 3), 256, 0, stream>>>(ys, W_out, yo);
    k_final<<<dim3(3072), 256, 0, stream>>>(x2, yo, out);
}

// Round 3
// 247.346 us; speedup vs baseline: 1.9205x; 1.4581x over previous
//
#include <hip/hip_runtime.h>

#define D_DIRS 4
#define BB 2
#define CC 96
#define LL 4096
#define PP 192
#define TWOP 384
#define NN 16
#define DTR 6
#define NPROJ 38
#define NCH 128
#define CLEN 32
#define SEQT 24576   // 8 db * 192 p * 16 n

typedef __bf16 bf16x8 __attribute__((ext_vector_type(8)));
typedef float f32x4 __attribute__((ext_vector_type(4)));

// time index t (within a direction's sequence) -> flat pixel offset h*64+w in x1
__device__ __forceinline__ int pixoff(int d, int t) {
    int tt = (d & 1) ? (LL - 1 - t) : t;
    if (d < 2) return tt;                      // seq_h: l = h*W + w
    return ((tt & 63) << 6) | (tt >> 6);       // seq_w: l = w*H + h -> pixel h*W+w
}

// ---------------- weight prep: fp32 -> padded bf16 images ----------------
// wbin: [4][384][104], wbx: [4][48][200] (j>=38 zeroed), wbout: [4][96][200]
__global__ void k_prep(const float* __restrict__ W_in, const float* __restrict__ W_x,
                       const float* __restrict__ W_out, __bf16* __restrict__ wbin,
                       __bf16* __restrict__ wbx, __bf16* __restrict__ wbout)
{
    int i = blockIdx.x * 256 + threadIdx.x;
    const int n0 = 4 * 384 * 104, n1 = 4 * 48 * 200, n2 = 4 * 96 * 200;
    if (i < n0) {
        int c = i % 104, jd = i / 104;          // jd = d*384 + j
        wbin[i] = (c < 96) ? (__bf16)W_in[jd * 96 + c] : (__bf16)0.0f;
    } else if (i < n0 + n1) {
        int k = i - n0;
        int c = k % 200, jd = k / 200;          // jd = d*48 + j
        int d = jd / 48, j = jd - d * 48;
        float v = (j < 38 && c < 192) ? W_x[(d * 38 + j) * 192 + c] : 0.0f;
        wbx[k] = (__bf16)v;
    } else if (i < n0 + n1 + n2) {
        int k = i - n0 - n1;
        int c = k % 200, jd = k / 200;          // jd = d*96 + cout
        float v = (c < 192) ? W_out[jd * 192 + c] : 0.0f;
        wbout[k] = (__bf16)v;
    }
}

// ---------------- input GEMM (MFMA): xz[m][j] = sum_c seq[m][c] * W_in[d][j][c] ----------------
__global__ __launch_bounds__(256) void k_gemm_in(
    const float* __restrict__ x1, const __bf16* __restrict__ wbin, float* __restrict__ xz)
{
    __shared__ __align__(16) __bf16 As[64 * 104];
    __shared__ __align__(16) __bf16 Bs[64 * 104];
    const int db = blockIdx.z;
    const int d = db >> 1, b = db & 1;
    const int t0 = blockIdx.x * 64;
    const int j0 = blockIdx.y * 64;
    const int tid = threadIdx.x;

    for (int i = tid; i < 64 * 96; i += 256) {
        int t = i & 63, c = i >> 6;
        int pix = pixoff(d, t0 + t);
        As[t * 104 + c] = (__bf16)x1[(b * CC + c) * LL + pix];
    }
    {
        const uint4* bsrc = reinterpret_cast<const uint4*>(wbin + (d * 384 + j0) * 104);
        uint4* bdst = reinterpret_cast<uint4*>(Bs);
        for (int i = tid; i < 832; i += 256) bdst[i] = bsrc[i];
    }
    __syncthreads();

    const int lane = tid & 63;
    const int w = tid >> 6;
    const int wm = (w >> 1) * 32, wn = (w & 1) * 32;
    const int lr = lane & 15, lk = (lane >> 4) * 8;
    const int orow = (lane >> 4) * 4;

    f32x4 acc[2][2] = {{{0.f,0.f,0.f,0.f},{0.f,0.f,0.f,0.f}},
                       {{0.f,0.f,0.f,0.f},{0.f,0.f,0.f,0.f}}};
#pragma unroll
    for (int ks = 0; ks < 96; ks += 32) {
        bf16x8 a0 = *(const bf16x8*)&As[(wm + lr) * 104 + ks + lk];
        bf16x8 a1 = *(const bf16x8*)&As[(wm + 16 + lr) * 104 + ks + lk];
        bf16x8 b0 = *(const bf16x8*)&Bs[(wn + lr) * 104 + ks + lk];
        bf16x8 b1 = *(const bf16x8*)&Bs[(wn + 16 + lr) * 104 + ks + lk];
        acc[0][0] = __builtin_amdgcn_mfma_f32_16x16x32_bf16(a0, b0, acc[0][0], 0, 0, 0);
        acc[0][1] = __builtin_amdgcn_mfma_f32_16x16x32_bf16(a0, b1, acc[0][1], 0, 0, 0);
        acc[1][0] = __builtin_amdgcn_mfma_f32_16x16x32_bf16(a1, b0, acc[1][0], 0, 0, 0);
        acc[1][1] = __builtin_amdgcn_mfma_f32_16x16x32_bf16(a1, b1, acc[1][1], 0, 0, 0);
    }
#pragma unroll
    for (int mi = 0; mi < 2; ++mi)
#pragma unroll
        for (int ni = 0; ni < 2; ++ni) {
            long base = ((long)(db * LL + t0 + wm + mi * 16 + orow)) * TWOP + j0 + wn + ni * 16 + lr;
#pragma unroll
            for (int r = 0; r < 4; ++r) xz[base + (long)r * TWOP] = acc[mi][ni][r];
        }
}

// ---------------- proj GEMM (MFMA): proj[m][j] = sum_k xbuf[m][k]*W_x[d][j][k], J=38 ----------------
__global__ __launch_bounds__(256) void k_gemm_proj(
    const float* __restrict__ Abuf, const __bf16* __restrict__ wbx, float* __restrict__ proj)
{
    __shared__ __align__(16) __bf16 As[64 * 200];
    __shared__ __align__(16) __bf16 Bs[48 * 200];
    const int m0 = blockIdx.x * 64;
    const int d = m0 >> 13;
    const int tid = threadIdx.x;

    for (int i = tid; i < 64 * 48; i += 256) {
        int t = i / 48, c4 = (i - t * 48) * 4;
        float4 v = *(const float4*)&Abuf[(long)(m0 + t) * PP + c4];
        union { __bf16 h[4]; uint2 u; } pk;
        pk.h[0] = (__bf16)v.x; pk.h[1] = (__bf16)v.y; pk.h[2] = (__bf16)v.z; pk.h[3] = (__bf16)v.w;
        *(uint2*)&As[t * 200 + c4] = pk.u;
    }
    {
        const uint4* bsrc = reinterpret_cast<const uint4*>(wbx + d * 48 * 200);
        uint4* bdst = reinterpret_cast<uint4*>(Bs);
        for (int i = tid; i < 1200; i += 256) bdst[i] = bsrc[i];
    }
    __syncthreads();

    const int lane = tid & 63;
    const int w = tid >> 6;                 // wave covers rows w*16..w*16+15
    const int lr = lane & 15, lk = (lane >> 4) * 8;
    const int orow = (lane >> 4) * 4;

    f32x4 acc[3] = {{0.f,0.f,0.f,0.f},{0.f,0.f,0.f,0.f},{0.f,0.f,0.f,0.f}};
#pragma unroll
    for (int ks = 0; ks < 192; ks += 32) {
        bf16x8 a = *(const bf16x8*)&As[(w * 16 + lr) * 200 + ks + lk];
#pragma unroll
        for (int ni = 0; ni < 3; ++ni) {
            bf16x8 bfr = *(const bf16x8*)&Bs[(ni * 16 + lr) * 200 + ks + lk];
            acc[ni] = __builtin_amdgcn_mfma_f32_16x16x32_bf16(a, bfr, acc[ni], 0, 0, 0);
        }
    }
#pragma unroll
    for (int ni = 0; ni < 3; ++ni) {
        int j = ni * 16 + lr;
        if (j < NPROJ) {
#pragma unroll
            for (int r = 0; r < 4; ++r) {
                int m = m0 + w * 16 + orow + r;
                proj[(long)m * NPROJ + j] = acc[ni][r];
            }
        }
    }
}

// ---------------- out GEMM (MFMA): yo[m][c] = sum_p ys[m][p]*W_out[d][c][p], J=96 ----------------
__global__ __launch_bounds__(256) void k_gemm_out(
    const float* __restrict__ Abuf, const __bf16* __restrict__ wbout, float* __restrict__ yo)
{
    __shared__ __align__(16) __bf16 As[64 * 200];
    __shared__ __align__(16) __bf16 Bs[96 * 200];
    const int m0 = blockIdx.x * 64;
    const int d = m0 >> 13;
    const int tid = threadIdx.x;

    for (int i = tid; i < 64 * 48; i += 256) {
        int t = i / 48, c4 = (i - t * 48) * 4;
        float4 v = *(const float4*)&Abuf[(long)(m0 + t) * PP + c4];
        union { __bf16 h[4]; uint2 u; } pk;
        pk.h[0] = (__bf16)v.x; pk.h[1] = (__bf16)v.y; pk.h[2] = (__bf16)v.z; pk.h[3] = (__bf16)v.w;
        *(uint2*)&As[t * 200 + c4] = pk.u;
    }
    {
        const uint4* bsrc = reinterpret_cast<const uint4*>(wbout + d * 96 * 200);
        uint4* bdst = reinterpret_cast<uint4*>(Bs);
        for (int i = tid; i < 2400; i += 256) bdst[i] = bsrc[i];
    }
    __syncthreads();

    const int lane = tid & 63;
    const int w = tid >> 6;
    const int wm = (w >> 1) * 32, wn = (w & 1) * 48;
    const int lr = lane & 15, lk = (lane >> 4) * 8;
    const int orow = (lane >> 4) * 4;

    f32x4 acc[2][3] = {};
#pragma unroll
    for (int ks = 0; ks < 192; ks += 32) {
        bf16x8 a0 = *(const bf16x8*)&As[(wm + lr) * 200 + ks + lk];
        bf16x8 a1 = *(const bf16x8*)&As[(wm + 16 + lr) * 200 + ks + lk];
#pragma unroll
        for (int ni = 0; ni < 3; ++ni) {
            bf16x8 bfr = *(const bf16x8*)&Bs[(wn + ni * 16 + lr) * 200 + ks + lk];
            acc[0][ni] = __builtin_amdgcn_mfma_f32_16x16x32_bf16(a0, bfr, acc[0][ni], 0, 0, 0);
            acc[1][ni] = __builtin_amdgcn_mfma_f32_16x16x32_bf16(a1, bfr, acc[1][ni], 0, 0, 0);
        }
    }
#pragma unroll
    for (int mi = 0; mi < 2; ++mi)
#pragma unroll
        for (int ni = 0; ni < 3; ++ni) {
#pragma unroll
            for (int r = 0; r < 4; ++r) {
                int m = m0 + wm + mi * 16 + orow + r;
                yo[(long)m * CC + wn + ni * 16 + lr] = acc[mi][ni][r];
            }
        }
}

// ---------------- depthwise causal conv (k=4) + bias + SiLU ----------------
__global__ void k_conv(const float* __restrict__ xz, const float* __restrict__ conv_w,
                       const float* __restrict__ conv_b, float* __restrict__ xbuf)
{
    int idx = blockIdx.x * blockDim.x + threadIdx.x;
    const int total = D_DIRS * BB * LL * PP;
    for (; idx < total; idx += gridDim.x * blockDim.x) {
        int p = idx % PP;
        int m = idx / PP;
        int t = m & (LL - 1);
        int d = m >> 13;
        float acc = conv_b[d * PP + p];
        const float* wp = conv_w + (d * PP + p) * 4;
#pragma unroll
        for (int k = 0; k < 4; ++k) {
            int tt = t - 3 + k;
            if (tt >= 0) acc += wp[k] * xz[(long)(m - 3 + k) * TWOP + p];
        }
        xbuf[(long)m * PP + p] = acc / (1.0f + __expf(-acc));
    }
}

// ---------------- scan pass 1: 1 thread per (p,chunk,db), 16 states in regs ----------------
__global__ __launch_bounds__(192) void k_pass1(
    const float* __restrict__ xbuf, const float* __restrict__ proj,
    const float* __restrict__ A_log, const float* __restrict__ W_dt,
    const float* __restrict__ b_dt,
    float* __restrict__ cb_pa, float* __restrict__ cb_h)
{
    __shared__ __align__(16) float pl[CLEN * 40];  // cols 0..5 = dtproj, 8..23 = B, 24..39 = C
    const int tid = threadIdx.x;      // = p
    const int chunk = blockIdx.x;
    const int db = blockIdx.y;
    const int d = db >> 1;
    const int m0 = db * LL + chunk * CLEN;

    const float* pr = proj + (long)m0 * NPROJ;
    for (int i = tid; i < CLEN * NPROJ; i += 192) {
        int r = i / NPROJ, c = i - r * NPROJ;
        int col = (c < 6) ? c : c + 2;
        pl[r * 40 + col] = pr[i];
    }

    const int p = tid;
    float A[16];
    const float* al = A_log + (d * PP + p) * NN;
#pragma unroll
    for (int n = 0; n < 16; ++n) A[n] = -__expf(al[n]);
    float w[6];
    const float* wd = W_dt + (d * PP + p) * DTR;
#pragma unroll
    for (int r = 0; r < 6; ++r) w[r] = wd[r];
    const float bdt = b_dt[d * PP + p];
    float h[16], pa[16];
#pragma unroll
    for (int n = 0; n < 16; ++n) { h[n] = 0.f; pa[n] = 1.f; }
    __syncthreads();

    const float* xp = xbuf + m0 * PP + p;
#pragma unroll 2
    for (int s = 0; s < CLEN; ++s) {
        const float* row = pl + s * 40;
        float v = bdt + row[0]*w[0] + row[1]*w[1] + row[2]*w[2]
                      + row[3]*w[3] + row[4]*w[4] + row[5]*w[5];
        float dtv = (v > 20.f) ? v : log1pf(__expf(v));
        float xv = xp[s * PP];
        float dtx = dtv * xv;
        const float4* B4 = reinterpret_cast<const float4*>(row + 8);
#pragma unroll
        for (int q = 0; q < 4; ++q) {
            float4 Bv = B4[q];
            float dA;
            dA = __expf(dtv * A[4*q+0]); h[4*q+0] = dA*h[4*q+0] + dtx*Bv.x; pa[4*q+0] *= dA;
            dA = __expf(dtv * A[4*q+1]); h[4*q+1] = dA*h[4*q+1] + dtx*Bv.y; pa[4*q+1] *= dA;
            dA = __expf(dtv * A[4*q+2]); h[4*q+2] = dA*h[4*q+2] + dtx*Bv.z; pa[4*q+2] *= dA;
            dA = __expf(dtv * A[4*q+3]); h[4*q+3] = dA*h[4*q+3] + dtx*Bv.w; pa[4*q+3] *= dA;
        }
    }
    const int seq = db * (PP * NN) + p * NN;
    float4* pao = reinterpret_cast<float4*>(cb_pa + (long)chunk * SEQT + seq);
    float4* ho  = reinterpret_cast<float4*>(cb_h  + (long)chunk * SEQT + seq);
#pragma unroll
    for (int q = 0; q < 4; ++q) {
        pao[q] = make_float4(pa[4*q], pa[4*q+1], pa[4*q+2], pa[4*q+3]);
        ho[q]  = make_float4(h[4*q],  h[4*q+1],  h[4*q+2],  h[4*q+3]);
    }
}

// ---------------- serial scan over chunks -> initial states ----------------
__global__ void k_chunkscan(const float* __restrict__ cb_pa, float* __restrict__ cb_h)
{
    int seq = blockIdx.x * 256 + threadIdx.x;   // 0..24575
    float run = 0.0f;
    for (int c = 0; c < NCH; ++c) {
        long o = (long)c * SEQT + seq;
        float pav = cb_pa[o];
        float hv = cb_h[o];
        cb_h[o] = run;
        run = pav * run + hv;
    }
}

// ---------------- scan pass 2: emit ys = (sum_n h*C + x*Dp) * silu(z) ----------------
__global__ __launch_bounds__(192) void k_pass2(
    const float* xbuf_in, const float* __restrict__ proj,
    const float* __restrict__ A_log, const float* __restrict__ W_dt,
    const float* __restrict__ b_dt, const float* __restrict__ Dp,
    const float* __restrict__ xz, const float* __restrict__ cb_h,
    float* ys)   // ys aliases xbuf_in: each element read-then-written by same thread
{
    __shared__ __align__(16) float pl[CLEN * 40];
    const int tid = threadIdx.x;
    const int chunk = blockIdx.x;
    const int db = blockIdx.y;
    const int d = db >> 1;
    const int m0 = db * LL + chunk * CLEN;

    const float* pr = proj + (long)m0 * NPROJ;
    for (int i = tid; i < CLEN * NPROJ; i += 192) {
        int r = i / NPROJ, c = i - r * NPROJ;
        int col = (c < 6) ? c : c + 2;
        pl[r * 40 + col] = pr[i];
    }

    const int p = tid;
    float A[16];
    const float* al = A_log + (d * PP + p) * NN;
#pragma unroll
    for (int n = 0; n < 16; ++n) A[n] = -__expf(al[n]);
    float w[6];
    const float* wd = W_dt + (d * PP + p) * DTR;
#pragma unroll
    for (int r = 0; r < 6; ++r) w[r] = wd[r];
    const float bdt = b_dt[d * PP + p];
    const float Dv = Dp[d * PP + p];

    float h[16];
    const int seq = db * (PP * NN) + p * NN;
    const float4* hi = reinterpret_cast<const float4*>(cb_h + (long)chunk * SEQT + seq);
#pragma unroll
    for (int q = 0; q < 4; ++q) {
        float4 hv = hi[q];
        h[4*q] = hv.x; h[4*q+1] = hv.y; h[4*q+2] = hv.z; h[4*q+3] = hv.w;
    }
    __syncthreads();

    const float* xp = xbuf_in + m0 * PP + p;
    const float* zp = xz + (long)m0 * TWOP + PP + p;
    float* yp = ys + m0 * PP + p;
#pragma unroll 2
    for (int s = 0; s < CLEN; ++s) {
        const float* row = pl + s * 40;
        float v = bdt + row[0]*w[0] + row[1]*w[1] + row[2]*w[2]
                      + row[3]*w[3] + row[4]*w[4] + row[5]*w[5];
        float dtv = (v > 20.f) ? v : log1pf(__expf(v));
        float xv = xp[s * PP];
        float dtx = dtv * xv;
        const float4* B4 = reinterpret_cast<const float4*>(row + 8);
        const float4* C4 = reinterpret_cast<const float4*>(row + 24);
        float y = 0.0f;
#pragma unroll
        for (int q = 0; q < 4; ++q) {
            float4 Bv = B4[q];
            float4 Cv = C4[q];
            float dA;
            dA = __expf(dtv * A[4*q+0]); h[4*q+0] = dA*h[4*q+0] + dtx*Bv.x; y += h[4*q+0]*Cv.x;
            dA = __expf(dtv * A[4*q+1]); h[4*q+1] = dA*h[4*q+1] + dtx*Bv.y; y += h[4*q+1]*Cv.y;
            dA = __expf(dtv * A[4*q+2]); h[4*q+2] = dA*h[4*q+2] + dtx*Bv.z; y += h[4*q+2]*Cv.z;
            dA = __expf(dtv * A[4*q+3]); h[4*q+3] = dA*h[4*q+3] + dtx*Bv.w; y += h[4*q+3]*Cv.w;
        }
        float zv = zp[s * TWOP];
        yp[s * PP] = (y + xv * Dv) * (zv / (1.0f + __expf(-zv)));
    }
}

// ---------------- final combine: out = x2 + sum of 4 directional outputs ----------------
__global__ void k_final(const float* __restrict__ x2, const float* __restrict__ yo,
                        float* __restrict__ out)
{
    int idx = blockIdx.x * blockDim.x + threadIdx.x;
    const int total = BB * CC * LL;
    for (; idx < total; idx += gridDim.x * blockDim.x) {
        int w = idx & 63;
        int h = (idx >> 6) & 63;
        int c = (idx >> 12) % CC;
        int b = idx / (CC * LL);
        int lh = (h << 6) | w;
        int lw = (w << 6) | h;
        long m0 = (long)(0 * BB + b) * LL + lh;
        long m1 = (long)(1 * BB + b) * LL + (LL - 1 - lh);
        long m2 = (long)(2 * BB + b) * LL + lw;
        long m3 = (long)(3 * BB + b) * LL + (LL - 1 - lw);
        out[idx] = x2[idx] + yo[m0 * CC + c] + yo[m1 * CC + c] + yo[m2 * CC + c] + yo[m3 * CC + c];
    }
}

extern "C" void kernel_launch(void* const* d_in, const int* in_sizes, int n_in,
                              void* d_out, int out_size, void* d_ws, size_t ws_size,
                              hipStream_t stream)
{
    const float* x1     = (const float*)d_in[0];
    const float* x2     = (const float*)d_in[1];
    const float* W_in   = (const float*)d_in[2];
    const float* conv_w = (const float*)d_in[3];
    const float* conv_b = (const float*)d_in[4];
    const float* W_x    = (const float*)d_in[5];
    const float* W_dt   = (const float*)d_in[6];
    const float* b_dt   = (const float*)d_in[7];
    const float* A_log  = (const float*)d_in[8];
    const float* Dp     = (const float*)d_in[9];
    const float* W_out  = (const float*)d_in[10];
    float* out = (float*)d_out;
    float* ws  = (float*)d_ws;

    // workspace layout (floats)
    float* xz    = ws;                // 12,582,912
    float* xbuf  = ws + 12582912;     // 6,291,456  (reused in-place as ys)
    float* proj  = ws + 18874368;     // 1,245,184
    float* cb_pa = ws + 20119552;     // 3,145,728
    float* cb_h  = ws + 23265280;     // 3,145,728
    float* yo    = ws + 26411008;     // 3,145,728
    __bf16* wbin = (__bf16*)(ws + 29556736);   // 159,744 bf16
    __bf16* wbx  = (__bf16*)(ws + 29636608);   // 38,400 bf16
    __bf16* wbout= (__bf16*)(ws + 29655808);   // 76,800 bf16
    float* ys = xbuf;

    k_prep<<<dim3(1074), 256, 0, stream>>>(W_in, W_x, W_out, wbin, wbx, wbout);
    k_gemm_in<<<dim3(64, 6, 8), 256, 0, stream>>>(x1, wbin, xz);
    k_conv<<<dim3(6144), 256, 0, stream>>>(xz, conv_w, conv_b, xbuf);
    k_gemm_proj<<<dim3(512), 256, 0, stream>>>(xbuf, wbx, proj);
    k_pass1<<<dim3(NCH, 8), 192, 0, stream>>>(xbuf, proj, A_log, W_dt, b_dt, cb_pa, cb_h);
    k_chunkscan<<<dim3(SEQT / 256), 256, 0, stream>>>(cb_pa, cb_h);
    k_pass2<<<dim3(NCH, 8), 192, 0, stream>>>(xbuf, proj, A_log, W_dt, b_dt, Dp, xz, cb_h, ys);
    k_gemm_out<<<dim3(512), 256, 0, stream>>>(ys, wbout, yo);
    k_final<<<dim3(3072), 256, 0, stream>>>(x2, yo, out);
}